// Round 11
// baseline (547.481 us; speedup 1.0000x reference)
//
#include <hip/hip_runtime.h>
#include <hip/hip_bf16.h>

#define LN_EPS 1e-5f

typedef __attribute__((ext_vector_type(8))) short short8v;
typedef __attribute__((ext_vector_type(4))) float float4v;

__device__ __forceinline__ float bflo(unsigned u) { return __uint_as_float(u << 16); }
__device__ __forceinline__ float bfhi(unsigned u) { return __uint_as_float(u & 0xffff0000u); }
__device__ __forceinline__ unsigned pack2(float x, float y) {
    __hip_bfloat162 t = __float22bfloat162_rn(make_float2(x, y));
    return *reinterpret_cast<unsigned*>(&t);
}
__device__ __forceinline__ void add8(float* a, uint4 u) {
    a[0] += bflo(u.x); a[1] += bfhi(u.x);
    a[2] += bflo(u.y); a[3] += bfhi(u.y);
    a[4] += bflo(u.z); a[5] += bfhi(u.z);
    a[6] += bflo(u.w); a[7] += bfhi(u.w);
}
__device__ __forceinline__ uint4 shfl4(uint4 v, int srcLane) {
    uint4 r;
    r.x = (unsigned)__shfl((int)v.x, srcLane);
    r.y = (unsigned)__shfl((int)v.y, srcLane);
    r.z = (unsigned)__shfl((int)v.z, srcLane);
    r.w = (unsigned)__shfl((int)v.w, srcLane);
    return r;
}

union U4S8 { uint4 u; short8v s; };

// ---------------- bucketed CSR build, fixed-capacity regions ----------------
// bucket b = dst >> 8 (256 nodes/bucket). Region b = [b*BCAP, b*BCAP+cnt_b).
// stage entry: src | (dst&0xff)<<24  (src < 2^24)

#define CHUNK 4096
#define NBMAX 512
#define BCAP 5120

__launch_bounds__(256)
__global__ void k_bucket(const int* __restrict__ src, const int* __restrict__ dst, int e,
                         int* __restrict__ gcnt, unsigned* __restrict__ stage) {
    __shared__ unsigned ebuf[CHUNK];
    __shared__ unsigned short ebkt[CHUNK];
    __shared__ int hist[NBMAX];
    __shared__ int base[NBMAX];
    int tid = threadIdx.x;
    int c0 = blockIdx.x * CHUNK;
    if (c0 >= e) return;
    int cnt = min(CHUNK, e - c0);

    for (int t = tid; t < NBMAX; t += 256) hist[t] = 0;
    __syncthreads();
    for (int t = tid; t < cnt; t += 256) {
        unsigned s = (unsigned)src[c0 + t];
        unsigned d = (unsigned)dst[c0 + t];
        ebuf[t] = s | ((d & 0xffu) << 24);
        ebkt[t] = (unsigned short)(d >> 8);
        atomicAdd(&hist[d >> 8], 1);
    }
    __syncthreads();
    for (int b = tid; b < NBMAX; b += 256) {
        int h = hist[b];
        if (h > 0) base[b] = b * BCAP + atomicAdd(&gcnt[b], h);
    }
    __syncthreads();
    for (int t = tid; t < cnt; t += 256) {
        int p = atomicAdd(&base[ebkt[t]], 1);
        stage[p] = ebuf[t];
    }
}

// pass 2: degrees -> row_start/row_end/dinv, direct global rank-scatter of CSR,
// AND pack x -> xb (pre-scaled by dinv).
__launch_bounds__(256)
__global__ void k_csr(const unsigned* __restrict__ stage, const int* __restrict__ gcnt,
                      int* __restrict__ csr_src, int* __restrict__ row_start,
                      int* __restrict__ row_end, float* __restrict__ dinv,
                      const float* __restrict__ x, unsigned* __restrict__ xb, int n) {
    __shared__ int cntl[256];
    __shared__ int sc[256];
    __shared__ int excl[256];
    __shared__ float dfl[256];
    int b = blockIdx.x;
    int lo = b << 8;
    int nn = min(n - lo, 256);
    int tid = threadIdx.x;
    int s0 = b * BCAP;
    int cntB = gcnt[b];

    cntl[tid] = 0;
    __syncthreads();
    for (int t = tid; t < cntB; t += 256) {
        int dl = (int)(stage[s0 + t] >> 24);
        atomicAdd(&cntl[dl], 1);
    }
    __syncthreads();
    int deg = (tid < nn) ? cntl[tid] : 0;
    sc[tid] = deg; __syncthreads();
    for (int o = 1; o < 256; o <<= 1) {
        int t = (tid >= o) ? sc[tid - o] : 0;
        __syncthreads();
        sc[tid] += t;
        __syncthreads();
    }
    excl[tid] = sc[tid] - deg;
    float dv = rsqrtf((float)(deg + 1));
    dfl[tid] = dv;
    if (tid < nn) {
        row_start[lo + tid] = s0 + excl[tid];
        row_end[lo + tid]   = s0 + excl[tid] + deg;
        dinv[lo + tid] = dv;
    }
    cntl[tid] = 0;
    __syncthreads();
    for (int t = tid; t < cntB; t += 256) {
        unsigned ed = stage[s0 + t];
        int dl = (int)(ed >> 24);
        int r = atomicAdd(&cntl[dl], 1);
        csr_src[s0 + excl[dl] + r] = (int)(ed & 0x00ffffffu);
    }

    const float4* x4 = (const float4*)x;
    uint2* xb2 = (uint2*)xb;
    for (int idx = tid; idx < nn * 16; idx += 256) {
        int node = idx >> 4, c = idx & 15;
        size_t p = ((size_t)(lo + node) << 4) + c;
        float4 v = x4[p];
        float d = dfl[node];
        xb2[p] = make_uint2(pack2(v.x * d, v.y * d), pack2(v.z * d, v.w * d));
    }
}

// per-graph reciprocal counts (batch sorted)
__global__ void k_rc(const int* __restrict__ batch, int n, float* __restrict__ rc) {
    int g = threadIdx.x;
    int lo = 0, hi = n;
    while (lo < hi) { int m = (lo + hi) >> 1; if (batch[m] < g) lo = m + 1; else hi = m; }
    int st = lo;
    hi = n;
    while (lo < hi) { int m = (lo + hi) >> 1; if (batch[m] < g + 1) lo = m + 1; else hi = m; }
    rc[g] = 1.f / fmaxf((float)(lo - st), 1.f);
}

// ---------------- FUSED agg64 + GEMM1 + LN + ReLU ----------------
// One wave per 16-row tile: aggregate each row (gather), shfl-redistribute the
// packed row into MFMA A-fragments, then MFMA + LN + relu + *dinv, store hb
// PERMUTED (column c=cb*16+lc at position lc*8+cb; one uint4 per reg per lane).

__launch_bounds__(256)
__global__ void k_f64mm1(const uint4* __restrict__ x4, const float* __restrict__ dinv,
                         const int* __restrict__ row_start, const int* __restrict__ row_end,
                         const int* __restrict__ csr_src,
                         const float* __restrict__ W1, const float* __restrict__ b1,
                         const float* __restrict__ g1, const float* __restrict__ be1,
                         uint4* __restrict__ hb4, int ntiles) {
    __shared__ uint4 sB[2 * 8 * 64];   // 16 KiB
    for (int idx = threadIdx.x; idx < 1024; idx += 256) {
        int l = idx & 63;
        int f = idx >> 6;
        int ks = f >> 3, cb = f & 7;
        int kb = ks * 32 + (l >> 4) * 8;
        int col = cb * 16 + (l & 15);
        float p[8];
        #pragma unroll
        for (int j = 0; j < 8; ++j) p[j] = W1[(kb + j) * 128 + col];
        uint4 v;
        v.x = pack2(p[0], p[1]); v.y = pack2(p[2], p[3]);
        v.z = pack2(p[4], p[5]); v.w = pack2(p[6], p[7]);
        sB[idx] = v;
    }
    __syncthreads();

    int lane = threadIdx.x & 63;
    int lc = lane & 15, lg = lane >> 4;
    int g8 = lane >> 3, c8 = lane & 7;
    int gwave = blockIdx.x * 4 + (threadIdx.x >> 6);
    int nwaves = gridDim.x * 4;

    float bs[8], gm[8], bt[8];
    #pragma unroll
    for (int cb = 0; cb < 8; ++cb) {
        bs[cb] = b1[cb * 16 + lc];
        gm[cb] = g1[cb * 16 + lc];
        bt[cb] = be1[cb * 16 + lc];
    }

    for (int t = gwave; t < ntiles; t += nwaves) {
        U4S8 A0, A1;
        for (int r = 0; r < 16; ++r) {
            int i = t * 16 + r;
            float a[8] = {0.f, 0.f, 0.f, 0.f, 0.f, 0.f, 0.f, 0.f};
            if (g8 == 0) {
                uint4 su = x4[(size_t)i * 8 + c8];
                add8(a, su);
            }
            int j0 = row_start[i], j1 = row_end[i];
            int j = j0 + g8;
            for (; j + 8 < j1; j += 16) {
                int s0 = csr_src[j], s1 = csr_src[j + 8];
                uint4 u0 = x4[(size_t)s0 * 8 + c8];
                uint4 u1 = x4[(size_t)s1 * 8 + c8];
                add8(a, u0);
                add8(a, u1);
            }
            if (j < j1) {
                int s0 = csr_src[j];
                uint4 u0 = x4[(size_t)s0 * 8 + c8];
                add8(a, u0);
            }
            #pragma unroll
            for (int k = 0; k < 8; ++k) {
                a[k] += __shfl_xor(a[k], 8);
                a[k] += __shfl_xor(a[k], 16);
                a[k] += __shfl_xor(a[k], 32);
            }
            float di = dinv[i];
            uint4 o;
            o.x = pack2(a[0] * di, a[1] * di);
            o.y = pack2(a[2] * di, a[3] * di);
            o.z = pack2(a[4] * di, a[5] * di);
            o.w = pack2(a[6] * di, a[7] * di);
            // lane holds row-r position c8; lane l needs positions lg and 4+lg
            uint4 p0 = shfl4(o, lg);
            uint4 p1 = shfl4(o, 4 + lg);
            if (lc == r) { A0.u = p0; A1.u = p1; }
        }
        float4v acc[8];
        #pragma unroll
        for (int cb = 0; cb < 8; ++cb) acc[cb] = (float4v){0.f, 0.f, 0.f, 0.f};
        #pragma unroll
        for (int cb = 0; cb < 8; ++cb) {
            U4S8 f0, f1;
            f0.u = sB[cb * 64 + lane];
            f1.u = sB[(8 + cb) * 64 + lane];
            acc[cb] = __builtin_amdgcn_mfma_f32_16x16x32_bf16(A0.s, f0.s, acc[cb], 0, 0, 0);
            acc[cb] = __builtin_amdgcn_mfma_f32_16x16x32_bf16(A1.s, f1.s, acc[cb], 0, 0, 0);
        }
        #pragma unroll
        for (int reg = 0; reg < 4; ++reg) {
            float s = 0.f, q = 0.f;
            #pragma unroll
            for (int cb = 0; cb < 8; ++cb) {
                float v = acc[cb][reg] + bs[cb];
                acc[cb][reg] = v;
                s += v; q = fmaf(v, v, q);
            }
            s += __shfl_xor(s, 1); q += __shfl_xor(q, 1);
            s += __shfl_xor(s, 2); q += __shfl_xor(q, 2);
            s += __shfl_xor(s, 4); q += __shfl_xor(q, 4);
            s += __shfl_xor(s, 8); q += __shfl_xor(q, 8);
            float mu = s * (1.f / 128.f);
            float var = fmaf(q, 1.f / 128.f, -mu * mu);
            float rstd = rsqrtf(var + LN_EPS);
            int rowi = t * 16 + lg * 4 + reg;
            float di = dinv[rowi];
            float o[8];
            #pragma unroll
            for (int cb = 0; cb < 8; ++cb)
                o[cb] = fmaxf(fmaf((acc[cb][reg] - mu) * rstd, gm[cb], bt[cb]), 0.f) * di;
            uint4 st;
            st.x = pack2(o[0], o[1]);
            st.y = pack2(o[2], o[3]);
            st.z = pack2(o[4], o[5]);
            st.w = pack2(o[6], o[7]);
            hb4[(size_t)rowi * 16 + lc] = st;   // permuted: pos = lc*8+cb
        }
    }
}

// ---------------- FUSED agg128 + GEMM2 + LN + pooled mean ----------------
// hb is permuted; aggregation is elementwise over positions so unaffected.
// sB packs W2 row c(s)=j*16+ks*4+lg into k-slot s (compensates permutation).

__launch_bounds__(256)
__global__ void k_f128mm2(const uint4* __restrict__ h4, const float* __restrict__ dinv,
                          const int* __restrict__ row_start, const int* __restrict__ row_end,
                          const int* __restrict__ csr_src,
                          const float* __restrict__ W2, const float* __restrict__ b2,
                          const float* __restrict__ g2, const float* __restrict__ be2,
                          const int* __restrict__ batch, const float* __restrict__ rc,
                          float* __restrict__ psum, int ntiles) {
    __shared__ uint4 sB[4 * 8 * 64];   // 32 KiB
    for (int idx = threadIdx.x; idx < 2048; idx += 256) {
        int l = idx & 63;
        int f = idx >> 6;
        int ks = f >> 3, cb = f & 7;
        int lg = l >> 4;
        int col = cb * 16 + (l & 15);
        float p[8];
        #pragma unroll
        for (int j = 0; j < 8; ++j)
            p[j] = W2[(j * 16 + ks * 4 + lg) * 128 + col];
        uint4 v;
        v.x = pack2(p[0], p[1]); v.y = pack2(p[2], p[3]);
        v.z = pack2(p[4], p[5]); v.w = pack2(p[6], p[7]);
        sB[idx] = v;
    }
    __syncthreads();

    int lane = threadIdx.x & 63;
    int lc = lane & 15, lg = lane >> 4;
    int gwave = blockIdx.x * 4 + (threadIdx.x >> 6);
    int nwaves = gridDim.x * 4;

    float bs[8], gm[8], bt[8];
    #pragma unroll
    for (int cb = 0; cb < 8; ++cb) {
        bs[cb] = b2[cb * 16 + lc];
        gm[cb] = g2[cb * 16 + lc];
        bt[cb] = be2[cb * 16 + lc];
    }

    for (int t = gwave; t < ntiles; t += nwaves) {
        U4S8 A[4];
        for (int r = 0; r < 16; ++r) {
            int i = t * 16 + r;
            float a[8] = {0.f, 0.f, 0.f, 0.f, 0.f, 0.f, 0.f, 0.f};
            if (lg == 0) {
                uint4 su = h4[(size_t)i * 16 + lc];
                add8(a, su);
            }
            int j0 = row_start[i], j1 = row_end[i];
            int j = j0 + lg;
            for (; j + 12 < j1; j += 16) {
                int s0 = csr_src[j], s1 = csr_src[j + 4];
                int s2 = csr_src[j + 8], s3 = csr_src[j + 12];
                uint4 u0 = h4[(size_t)s0 * 16 + lc];
                uint4 u1 = h4[(size_t)s1 * 16 + lc];
                uint4 u2 = h4[(size_t)s2 * 16 + lc];
                uint4 u3 = h4[(size_t)s3 * 16 + lc];
                add8(a, u0);
                add8(a, u1);
                add8(a, u2);
                add8(a, u3);
            }
            for (; j < j1; j += 4) {
                int s0 = csr_src[j];
                uint4 u0 = h4[(size_t)s0 * 16 + lc];
                add8(a, u0);
            }
            #pragma unroll
            for (int k = 0; k < 8; ++k) {
                a[k] += __shfl_xor(a[k], 16);
                a[k] += __shfl_xor(a[k], 32);
            }
            float di = dinv[i];
            uint4 o;
            o.x = pack2(a[0] * di, a[1] * di);
            o.y = pack2(a[2] * di, a[3] * di);
            o.z = pack2(a[4] * di, a[5] * di);
            o.w = pack2(a[6] * di, a[7] * di);
            // lane holds row-r position lc; lane l needs positions ks*4+lg
            #pragma unroll
            for (int ks = 0; ks < 4; ++ks) {
                uint4 pk = shfl4(o, ks * 4 + lg);
                if (lc == r) A[ks].u = pk;
            }
        }
        float4v acc[8];
        #pragma unroll
        for (int cb = 0; cb < 8; ++cb) acc[cb] = (float4v){0.f, 0.f, 0.f, 0.f};
        #pragma unroll
        for (int ks = 0; ks < 4; ++ks) {
            #pragma unroll
            for (int cb = 0; cb < 8; ++cb) {
                U4S8 fb;
                fb.u = sB[(ks * 8 + cb) * 64 + lane];
                acc[cb] = __builtin_amdgcn_mfma_f32_16x16x32_bf16(A[ks].s, fb.s, acc[cb], 0, 0, 0);
            }
        }
        #pragma unroll
        for (int reg = 0; reg < 4; ++reg) {
            float s = 0.f, q = 0.f;
            #pragma unroll
            for (int cb = 0; cb < 8; ++cb) {
                float v = acc[cb][reg] + bs[cb];
                acc[cb][reg] = v;
                s += v; q = fmaf(v, v, q);
            }
            s += __shfl_xor(s, 1); q += __shfl_xor(q, 1);
            s += __shfl_xor(s, 2); q += __shfl_xor(q, 2);
            s += __shfl_xor(s, 4); q += __shfl_xor(q, 4);
            s += __shfl_xor(s, 8); q += __shfl_xor(q, 8);
            float mu = s * (1.f / 128.f);
            float var = fmaf(q, 1.f / 128.f, -mu * mu);
            float rstd = rsqrtf(var + LN_EPS);
            #pragma unroll
            for (int cb = 0; cb < 8; ++cb)
                acc[cb][reg] = fmaf((acc[cb][reg] - mu) * rstd, gm[cb], bt[cb]);
        }
        int row0 = t * 16;
        int gmin = batch[row0];
        int gmax = batch[row0 + 15];
        int rg[4];
        #pragma unroll
        for (int reg = 0; reg < 4; ++reg) rg[reg] = batch[row0 + lg * 4 + reg];
        for (int g = gmin; g <= gmax; ++g) {
            float rcg = rc[g];
            #pragma unroll
            for (int cb = 0; cb < 8; ++cb) {
                float s = 0.f;
                #pragma unroll
                for (int reg = 0; reg < 4; ++reg)
                    s += (rg[reg] == g) ? acc[cb][reg] : 0.f;
                s += __shfl_xor(s, 16);
                s += __shfl_xor(s, 32);
                if (lg == 0) atomicAdd(&psum[g * 128 + cb * 16 + lc], s * rcg);
            }
        }
    }
}

// ---------------- launch ----------------

extern "C" void kernel_launch(void* const* d_in, const int* in_sizes, int n_in,
                              void* d_out, int out_size, void* d_ws, size_t ws_size,
                              hipStream_t stream) {
    const float* x   = (const float*)d_in[0];
    const int*   ei  = (const int*)d_in[1];
    const int*   bat = (const int*)d_in[2];
    const float* W1  = (const float*)d_in[3];
    const float* b1  = (const float*)d_in[4];
    const float* g1  = (const float*)d_in[5];
    const float* be1 = (const float*)d_in[6];
    const float* W2  = (const float*)d_in[7];
    const float* b2  = (const float*)d_in[8];
    const float* g2  = (const float*)d_in[9];
    const float* be2 = (const float*)d_in[10];

    int n = in_sizes[0] / 64;     // 100000
    int e = in_sizes[1] / 2;      // 1600000
    int G = out_size / 128;       // 128
    const int* src = ei;
    const int* dst = ei + e;

    int nbuckets = (n + 255) / 256;                 // 391

    char* ws = (char*)d_ws;
    size_t off = 0;
    auto take = [&](size_t bytes) -> void* {
        void* p = ws + off;
        off = (off + bytes + 255) & ~(size_t)255;
        return p;
    };
    float*    dinv      = (float*)   take((size_t)n * 4);
    int*      row_start = (int*)     take((size_t)n * 4);
    int*      row_end   = (int*)     take((size_t)n * 4);
    int*      gcnt      = (int*)     take(NBMAX * 4);
    float*    rcbuf     = (float*)   take((size_t)G * 4);
    unsigned* stage     = (unsigned*)take((size_t)nbuckets * BCAP * 4);
    int*      csr_src   = (int*)     take((size_t)nbuckets * BCAP * 4);
    unsigned* xb        = (unsigned*)take((size_t)n * 64 * 2);
    unsigned* hb        = (unsigned*)take((size_t)n * 128 * 2);

    hipMemsetAsync(gcnt, 0, NBMAX * 4, stream);
    hipMemsetAsync(d_out, 0, (size_t)out_size * 4, stream);

    int nbk = (e + CHUNK - 1) / CHUNK;
    k_bucket<<<nbk, 256, 0, stream>>>(src, dst, e, gcnt, stage);
    k_csr<<<nbuckets, 256, 0, stream>>>(stage, gcnt, csr_src, row_start, row_end,
                                        dinv, x, xb, n);
    k_rc<<<1, G, 0, stream>>>(bat, n, rcbuf);

    int ntiles = n / 16;  // 6250
    int fblocks = (ntiles + 3) / 4;   // 1563, one tile per wave

    k_f64mm1<<<fblocks, 256, 0, stream>>>((const uint4*)xb, dinv, row_start, row_end,
                                          csr_src, W1, b1, g1, be1,
                                          (uint4*)hb, ntiles);

    k_f128mm2<<<fblocks, 256, 0, stream>>>((const uint4*)hb, dinv, row_start, row_end,
                                           csr_src, W2, b2, g2, be2, bat, rcbuf,
                                           (float*)d_out, ntiles);
}

// Round 12
// 215.100 us; speedup vs baseline: 2.5452x; 2.5452x over previous
//
#include <hip/hip_runtime.h>
#include <hip/hip_bf16.h>

#define LN_EPS 1e-5f

typedef __attribute__((ext_vector_type(8))) short short8v;
typedef __attribute__((ext_vector_type(4))) float float4v;

__device__ __forceinline__ float bflo(unsigned u) { return __uint_as_float(u << 16); }
__device__ __forceinline__ float bfhi(unsigned u) { return __uint_as_float(u & 0xffff0000u); }
__device__ __forceinline__ unsigned pack2(float x, float y) {
    __hip_bfloat162 t = __float22bfloat162_rn(make_float2(x, y));
    return *reinterpret_cast<unsigned*>(&t);
}
__device__ __forceinline__ void add8(float* a, uint4 u) {
    a[0] += bflo(u.x); a[1] += bfhi(u.x);
    a[2] += bflo(u.y); a[3] += bfhi(u.y);
    a[4] += bflo(u.z); a[5] += bfhi(u.z);
    a[6] += bflo(u.w); a[7] += bfhi(u.w);
}

union U4S8 { uint4 u; short8v s; };

// ---------------- bucketed CSR build, fixed-capacity regions ----------------
// bucket b = dst >> 8 (256 nodes/bucket). Region b = [b*BCAP, b*BCAP+cnt_b).
// stage entry: src | (dst&0xff)<<24  (src < 2^24)

#define CHUNK 4096
#define NBMAX 512
#define BCAP 5120

__launch_bounds__(256)
__global__ void k_bucket(const int* __restrict__ src, const int* __restrict__ dst, int e,
                         int* __restrict__ gcnt, unsigned* __restrict__ stage) {
    __shared__ unsigned ebuf[CHUNK];
    __shared__ unsigned short ebkt[CHUNK];
    __shared__ int hist[NBMAX];
    __shared__ int base[NBMAX];
    int tid = threadIdx.x;
    int c0 = blockIdx.x * CHUNK;
    if (c0 >= e) return;
    int cnt = min(CHUNK, e - c0);

    for (int t = tid; t < NBMAX; t += 256) hist[t] = 0;
    __syncthreads();
    for (int t = tid; t < cnt; t += 256) {
        unsigned s = (unsigned)src[c0 + t];
        unsigned d = (unsigned)dst[c0 + t];
        ebuf[t] = s | ((d & 0xffu) << 24);
        ebkt[t] = (unsigned short)(d >> 8);
        atomicAdd(&hist[d >> 8], 1);
    }
    __syncthreads();
    for (int b = tid; b < NBMAX; b += 256) {
        int h = hist[b];
        if (h > 0) base[b] = b * BCAP + atomicAdd(&gcnt[b], h);
    }
    __syncthreads();
    for (int t = tid; t < cnt; t += 256) {
        int p = atomicAdd(&base[ebkt[t]], 1);
        stage[p] = ebuf[t];
    }
}

// pass 2: degrees -> row_start/row_end/dinv, direct global rank-scatter of CSR
// (region is L2-resident so scattered 4B stores coalesce in L2), AND pack x -> xb.
__launch_bounds__(256)
__global__ void k_csr(const unsigned* __restrict__ stage, const int* __restrict__ gcnt,
                      int* __restrict__ csr_src, int* __restrict__ row_start,
                      int* __restrict__ row_end, float* __restrict__ dinv,
                      const float* __restrict__ x, unsigned* __restrict__ xb, int n) {
    __shared__ int cntl[256];
    __shared__ int sc[256];
    __shared__ int excl[256];
    __shared__ float dfl[256];
    int b = blockIdx.x;
    int lo = b << 8;
    int nn = min(n - lo, 256);
    int tid = threadIdx.x;
    int s0 = b * BCAP;
    int cntB = gcnt[b];

    cntl[tid] = 0;
    __syncthreads();
    for (int t = tid; t < cntB; t += 256) {
        int dl = (int)(stage[s0 + t] >> 24);
        atomicAdd(&cntl[dl], 1);
    }
    __syncthreads();
    int deg = (tid < nn) ? cntl[tid] : 0;
    sc[tid] = deg; __syncthreads();
    for (int o = 1; o < 256; o <<= 1) {
        int t = (tid >= o) ? sc[tid - o] : 0;
        __syncthreads();
        sc[tid] += t;
        __syncthreads();
    }
    excl[tid] = sc[tid] - deg;
    float dv = rsqrtf((float)(deg + 1));
    dfl[tid] = dv;
    if (tid < nn) {
        row_start[lo + tid] = s0 + excl[tid];
        row_end[lo + tid]   = s0 + excl[tid] + deg;
        dinv[lo + tid] = dv;
    }
    cntl[tid] = 0;
    __syncthreads();
    for (int t = tid; t < cntB; t += 256) {
        unsigned ed = stage[s0 + t];
        int dl = (int)(ed >> 24);
        int r = atomicAdd(&cntl[dl], 1);
        csr_src[s0 + excl[dl] + r] = (int)(ed & 0x00ffffffu);
    }

    // pack x rows [lo, lo+nn) -> xb, scaled by dinv (float4 -> uint2)
    const float4* x4 = (const float4*)x;
    uint2* xb2 = (uint2*)xb;
    for (int idx = tid; idx < nn * 16; idx += 256) {
        int node = idx >> 4, c = idx & 15;
        size_t p = ((size_t)(lo + node) << 4) + c;
        float4 v = x4[p];
        float d = dfl[node];
        xb2[p] = make_uint2(pack2(v.x * d, v.y * d), pack2(v.z * d, v.w * d));
    }
}

// per-graph reciprocal counts (batch sorted)
__global__ void k_rc(const int* __restrict__ batch, int n, float* __restrict__ rc) {
    int g = threadIdx.x;
    int lo = 0, hi = n;
    while (lo < hi) { int m = (lo + hi) >> 1; if (batch[m] < g) lo = m + 1; else hi = m; }
    int st = lo;
    hi = n;
    while (lo < hi) { int m = (lo + hi) >> 1; if (batch[m] < g + 1) lo = m + 1; else hi = m; }
    rc[g] = 1.f / fmaxf((float)(lo - st), 1.f);
}

// ---------------- Aggregation: out[d] = dinv[d] * (x'[d] + sum x'[s]) ----------------

__global__ void k_agg64b(const uint4* __restrict__ x4, const float* __restrict__ dinv,
                         const int* __restrict__ row_start, const int* __restrict__ row_end,
                         const int* __restrict__ csr_src, uint4* __restrict__ out4, int n) {
    int lane = threadIdx.x & 63;
    int g = lane >> 3, c = lane & 7;
    int wid = (blockIdx.x * blockDim.x + threadIdx.x) >> 6;
    int nw = (gridDim.x * blockDim.x) >> 6;
    for (int i = wid; i < n; i += nw) {
        float a[8] = {0.f, 0.f, 0.f, 0.f, 0.f, 0.f, 0.f, 0.f};
        if (g == 0) {
            uint4 su = x4[(size_t)i * 8 + c];
            add8(a, su);
        }
        int j0 = row_start[i], j1 = row_end[i];
        int j = j0 + g;
        for (; j + 8 < j1; j += 16) {
            int s0 = csr_src[j], s1 = csr_src[j + 8];
            uint4 u0 = x4[(size_t)s0 * 8 + c];
            uint4 u1 = x4[(size_t)s1 * 8 + c];
            add8(a, u0);
            add8(a, u1);
        }
        if (j < j1) {
            int s0 = csr_src[j];
            uint4 u0 = x4[(size_t)s0 * 8 + c];
            add8(a, u0);
        }
        #pragma unroll
        for (int k = 0; k < 8; ++k) {
            a[k] += __shfl_xor(a[k], 8);
            a[k] += __shfl_xor(a[k], 16);
            a[k] += __shfl_xor(a[k], 32);
        }
        if (g == 0) {
            float di = dinv[i];
            uint4 o;
            o.x = pack2(a[0] * di, a[1] * di);
            o.y = pack2(a[2] * di, a[3] * di);
            o.z = pack2(a[4] * di, a[5] * di);
            o.w = pack2(a[6] * di, a[7] * di);
            out4[(size_t)i * 8 + c] = o;
        }
    }
}

__global__ void k_agg128b(const uint4* __restrict__ h4, const float* __restrict__ dinv,
                          const int* __restrict__ row_start, const int* __restrict__ row_end,
                          const int* __restrict__ csr_src, uint4* __restrict__ out4, int n) {
    int lane = threadIdx.x & 63;
    int q = lane >> 4, c = lane & 15;
    int wid = (blockIdx.x * blockDim.x + threadIdx.x) >> 6;
    int nw = (gridDim.x * blockDim.x) >> 6;
    for (int i = wid; i < n; i += nw) {
        float a[8] = {0.f, 0.f, 0.f, 0.f, 0.f, 0.f, 0.f, 0.f};
        if (q == 0) {
            uint4 su = h4[(size_t)i * 16 + c];
            add8(a, su);
        }
        int j0 = row_start[i], j1 = row_end[i];
        int j = j0 + q;
        for (; j + 12 < j1; j += 16) {
            int s0 = csr_src[j], s1 = csr_src[j + 4];
            int s2 = csr_src[j + 8], s3 = csr_src[j + 12];
            uint4 u0 = h4[(size_t)s0 * 16 + c];
            uint4 u1 = h4[(size_t)s1 * 16 + c];
            uint4 u2 = h4[(size_t)s2 * 16 + c];
            uint4 u3 = h4[(size_t)s3 * 16 + c];
            add8(a, u0);
            add8(a, u1);
            add8(a, u2);
            add8(a, u3);
        }
        for (; j < j1; j += 4) {
            int s0 = csr_src[j];
            uint4 u0 = h4[(size_t)s0 * 16 + c];
            add8(a, u0);
        }
        #pragma unroll
        for (int k = 0; k < 8; ++k) {
            a[k] += __shfl_xor(a[k], 16);
            a[k] += __shfl_xor(a[k], 32);
        }
        if (q == 0) {
            float di = dinv[i];
            uint4 o;
            o.x = pack2(a[0] * di, a[1] * di);
            o.y = pack2(a[2] * di, a[3] * di);
            o.z = pack2(a[4] * di, a[5] * di);
            o.w = pack2(a[6] * di, a[7] * di);
            out4[(size_t)i * 16 + c] = o;
        }
    }
}

// ---------------- MFMA GEMM + LN (+ReLU) fused ----------------
// mfma_f32_16x16x32_bf16. A/B frag: k-slot = (lane>>4)*8 + j. C/D: col=lane&15, row=(lane>>4)*4+reg.
//
// PERMUTED h LAYOUT: mm1 stores column c = cb*16+lc at position p = lc*8+cb
// (one uint4 per reg per lane). Elementwise agg/dinv commute with the permutation;
// mm2p compensates by packing W2 row c(s) = j*16+ks*4+lg into k-slot s.

// agg[N][64] bf16 @ W1[64][128] -> LN -> relu -> *dinv[row] -> hb[N][128] bf16 (permuted)
__launch_bounds__(256)
__global__ void k_mm1(const unsigned* __restrict__ aggb, const float* __restrict__ W1,
                      const float* __restrict__ b1, const float* __restrict__ g1,
                      const float* __restrict__ be1, const float* __restrict__ dinv,
                      uint4* __restrict__ hb4, int ntiles) {
    __shared__ uint4 sB[2 * 8 * 64];   // 16 KiB: frag (ks*8+cb), lane
    for (int idx = threadIdx.x; idx < 1024; idx += blockDim.x) {
        int l = idx & 63;
        int f = idx >> 6;
        int ks = f >> 3, cb = f & 7;
        int kb = ks * 32 + (l >> 4) * 8;
        int col = cb * 16 + (l & 15);
        float p[8];
        #pragma unroll
        for (int j = 0; j < 8; ++j) p[j] = W1[(kb + j) * 128 + col];
        uint4 v;
        v.x = pack2(p[0], p[1]); v.y = pack2(p[2], p[3]);
        v.z = pack2(p[4], p[5]); v.w = pack2(p[6], p[7]);
        sB[idx] = v;
    }
    __syncthreads();

    int lane = threadIdx.x & 63;
    int wv = threadIdx.x >> 6;
    int wpb = blockDim.x >> 6;
    int lc = lane & 15, lg = lane >> 4;

    // copy B fragments to registers once (register-resident main loop)
    U4S8 B[2][8];
    #pragma unroll
    for (int ks = 0; ks < 2; ++ks)
        #pragma unroll
        for (int cb = 0; cb < 8; ++cb)
            B[ks][cb].u = sB[(ks * 8 + cb) * 64 + lane];

    float bs[8], gm[8], bt[8];
    #pragma unroll
    for (int cb = 0; cb < 8; ++cb) {
        bs[cb] = b1[cb * 16 + lc];
        gm[cb] = g1[cb * 16 + lc];
        bt[cb] = be1[cb * 16 + lc];
    }

    for (int t = blockIdx.x * wpb + wv; t < ntiles; t += gridDim.x * wpb) {
        size_t arow = (size_t)(t * 16 + lc) * 32;
        U4S8 a0, a1;
        a0.u = *(const uint4*)&aggb[arow + lg * 4];
        a1.u = *(const uint4*)&aggb[arow + 16 + lg * 4];
        float4v acc[8];
        #pragma unroll
        for (int cb = 0; cb < 8; ++cb) acc[cb] = (float4v){0.f, 0.f, 0.f, 0.f};
        #pragma unroll
        for (int cb = 0; cb < 8; ++cb) {
            acc[cb] = __builtin_amdgcn_mfma_f32_16x16x32_bf16(a0.s, B[0][cb].s, acc[cb], 0, 0, 0);
            acc[cb] = __builtin_amdgcn_mfma_f32_16x16x32_bf16(a1.s, B[1][cb].s, acc[cb], 0, 0, 0);
        }
        #pragma unroll
        for (int reg = 0; reg < 4; ++reg) {
            float s = 0.f, q = 0.f;
            #pragma unroll
            for (int cb = 0; cb < 8; ++cb) {
                float v = acc[cb][reg] + bs[cb];
                acc[cb][reg] = v;
                s += v; q = fmaf(v, v, q);
            }
            s += __shfl_xor(s, 1); q += __shfl_xor(q, 1);
            s += __shfl_xor(s, 2); q += __shfl_xor(q, 2);
            s += __shfl_xor(s, 4); q += __shfl_xor(q, 4);
            s += __shfl_xor(s, 8); q += __shfl_xor(q, 8);
            float mu = s * (1.f / 128.f);
            float var = fmaf(q, 1.f / 128.f, -mu * mu);
            float rstd = rsqrtf(var + LN_EPS);
            int rowi = t * 16 + lg * 4 + reg;
            float di = dinv[rowi];
            float o[8];
            #pragma unroll
            for (int cb = 0; cb < 8; ++cb)
                o[cb] = fmaxf(fmaf((acc[cb][reg] - mu) * rstd, gm[cb], bt[cb]), 0.f) * di;
            uint4 st;
            st.x = pack2(o[0], o[1]);
            st.y = pack2(o[2], o[3]);
            st.z = pack2(o[4], o[5]);
            st.w = pack2(o[6], o[7]);
            hb4[(size_t)rowi * 16 + lc] = st;   // permuted: pos = lc*8+cb
        }
    }
}

// agg2[N][128] bf16 (permuted) @ W2[128][128] -> LN -> scaled pooled atomicAdd into out[G][128]
__launch_bounds__(256)
__global__ void k_mm2p(const unsigned* __restrict__ aggb, const float* __restrict__ W2,
                       const float* __restrict__ b2, const float* __restrict__ g2,
                       const float* __restrict__ be2, const int* __restrict__ batch,
                       const float* __restrict__ rc, float* __restrict__ psum, int ntiles) {
    __shared__ uint4 sB[4 * 8 * 64];   // 32 KiB
    for (int idx = threadIdx.x; idx < 2048; idx += blockDim.x) {
        int l = idx & 63;
        int f = idx >> 6;
        int ks = f >> 3, cb = f & 7;
        int lg = l >> 4;
        int col = cb * 16 + (l & 15);
        float p[8];
        #pragma unroll
        for (int j = 0; j < 8; ++j)
            p[j] = W2[(j * 16 + ks * 4 + lg) * 128 + col];   // permuted k-slot -> column
        uint4 v;
        v.x = pack2(p[0], p[1]); v.y = pack2(p[2], p[3]);
        v.z = pack2(p[4], p[5]); v.w = pack2(p[6], p[7]);
        sB[idx] = v;
    }
    __syncthreads();

    int lane = threadIdx.x & 63;
    int wv = threadIdx.x >> 6;
    int wpb = blockDim.x >> 6;
    int lc = lane & 15, lg = lane >> 4;
    float bs[8], gm[8], bt[8];
    #pragma unroll
    for (int cb = 0; cb < 8; ++cb) {
        bs[cb] = b2[cb * 16 + lc];
        gm[cb] = g2[cb * 16 + lc];
        bt[cb] = be2[cb * 16 + lc];
    }

    for (int t = blockIdx.x * wpb + wv; t < ntiles; t += gridDim.x * wpb) {
        int row0 = t * 16;
        size_t arow = (size_t)(row0 + lc) * 64;
        U4S8 a[4];
        #pragma unroll
        for (int ks = 0; ks < 4; ++ks)
            a[ks].u = *(const uint4*)&aggb[arow + ks * 16 + lg * 4];
        float4v acc[8];
        #pragma unroll
        for (int cb = 0; cb < 8; ++cb) acc[cb] = (float4v){0.f, 0.f, 0.f, 0.f};
        #pragma unroll
        for (int ks = 0; ks < 4; ++ks) {
            #pragma unroll
            for (int cb = 0; cb < 8; ++cb) {
                U4S8 fb;
                fb.u = sB[(ks * 8 + cb) * 64 + lane];
                acc[cb] = __builtin_amdgcn_mfma_f32_16x16x32_bf16(a[ks].s, fb.s, acc[cb], 0, 0, 0);
            }
        }
        #pragma unroll
        for (int reg = 0; reg < 4; ++reg) {
            float s = 0.f, q = 0.f;
            #pragma unroll
            for (int cb = 0; cb < 8; ++cb) {
                float v = acc[cb][reg] + bs[cb];
                acc[cb][reg] = v;
                s += v; q = fmaf(v, v, q);
            }
            s += __shfl_xor(s, 1); q += __shfl_xor(q, 1);
            s += __shfl_xor(s, 2); q += __shfl_xor(q, 2);
            s += __shfl_xor(s, 4); q += __shfl_xor(q, 4);
            s += __shfl_xor(s, 8); q += __shfl_xor(q, 8);
            float mu = s * (1.f / 128.f);
            float var = fmaf(q, 1.f / 128.f, -mu * mu);
            float rstd = rsqrtf(var + LN_EPS);
            #pragma unroll
            for (int cb = 0; cb < 8; ++cb)
                acc[cb][reg] = fmaf((acc[cb][reg] - mu) * rstd, gm[cb], bt[cb]);
        }
        int gmin = batch[row0];
        int gmax = batch[row0 + 15];
        int rg[4];
        #pragma unroll
        for (int reg = 0; reg < 4; ++reg) rg[reg] = batch[row0 + lg * 4 + reg];
        for (int g = gmin; g <= gmax; ++g) {
            float rcg = rc[g];
            #pragma unroll
            for (int cb = 0; cb < 8; ++cb) {
                float s = 0.f;
                #pragma unroll
                for (int reg = 0; reg < 4; ++reg)
                    s += (rg[reg] == g) ? acc[cb][reg] : 0.f;
                s += __shfl_xor(s, 16);
                s += __shfl_xor(s, 32);
                if (lg == 0) atomicAdd(&psum[g * 128 + cb * 16 + lc], s * rcg);
            }
        }
    }
}

// ---------------- launch ----------------

extern "C" void kernel_launch(void* const* d_in, const int* in_sizes, int n_in,
                              void* d_out, int out_size, void* d_ws, size_t ws_size,
                              hipStream_t stream) {
    const float* x   = (const float*)d_in[0];
    const int*   ei  = (const int*)d_in[1];
    const int*   bat = (const int*)d_in[2];
    const float* W1  = (const float*)d_in[3];
    const float* b1  = (const float*)d_in[4];
    const float* g1  = (const float*)d_in[5];
    const float* be1 = (const float*)d_in[6];
    const float* W2  = (const float*)d_in[7];
    const float* b2  = (const float*)d_in[8];
    const float* g2  = (const float*)d_in[9];
    const float* be2 = (const float*)d_in[10];

    int n = in_sizes[0] / 64;     // 100000
    int e = in_sizes[1] / 2;      // 1600000
    int G = out_size / 128;       // 128
    const int* src = ei;
    const int* dst = ei + e;

    int nbuckets = (n + 255) / 256;                 // 391

    char* ws = (char*)d_ws;
    size_t off = 0;
    auto take = [&](size_t bytes) -> void* {
        void* p = ws + off;
        off = (off + bytes + 255) & ~(size_t)255;
        return p;
    };
    float*    dinv      = (float*)   take((size_t)n * 4);
    int*      row_start = (int*)     take((size_t)n * 4);
    int*      row_end   = (int*)     take((size_t)n * 4);
    int*      gcnt      = (int*)     take(NBMAX * 4);
    float*    rcbuf     = (float*)   take((size_t)G * 4);
    unsigned* stage     = (unsigned*)take((size_t)nbuckets * BCAP * 4);
    int*      csr_src   = (int*)     take((size_t)nbuckets * BCAP * 4);
    unsigned* xb        = (unsigned*)take((size_t)n * 64 * 2);
    unsigned* aggb      = (unsigned*)take((size_t)n * 64 * 2);
    unsigned* hb        = (unsigned*)take((size_t)n * 128 * 2);
    unsigned* agg2b     = (unsigned*)take((size_t)n * 128 * 2);

    hipMemsetAsync(gcnt, 0, NBMAX * 4, stream);
    hipMemsetAsync(d_out, 0, (size_t)out_size * 4, stream);

    int nbk = (e + CHUNK - 1) / CHUNK;
    k_bucket<<<nbk, 256, 0, stream>>>(src, dst, e, gcnt, stage);
    k_csr<<<nbuckets, 256, 0, stream>>>(stage, gcnt, csr_src, row_start, row_end,
                                        dinv, x, xb, n);
    k_rc<<<1, G, 0, stream>>>(bat, n, rcbuf);

    k_agg64b<<<2048, 256, 0, stream>>>((const uint4*)xb, dinv, row_start, row_end,
                                       csr_src, (uint4*)aggb, n);

    int ntiles = n / 16;  // 6250
    k_mm1<<<626, 256, 0, stream>>>(aggb, W1, b1, g1, be1, dinv,
                                   (uint4*)hb, ntiles);

    k_agg128b<<<2048, 256, 0, stream>>>((const uint4*)hb, dinv, row_start, row_end,
                                        csr_src, (uint4*)agg2b, n);

    k_mm2p<<<626, 256, 0, stream>>>(agg2b, W2, b2, g2, be2, bat, rcbuf,
                                    (float*)d_out, ntiles);
}